// Round 1
// baseline (1547.561 us; speedup 1.0000x reference)
//
#include <hip/hip_runtime.h>

#define TSTEPS 30
#define KPAD 168   // 160 K-elems + 8 pad -> 336B row stride; m*336 mod 128 cycles all 16B slots (2-way, free)

typedef _Float16 half8 __attribute__((ext_vector_type(8)));
typedef float f32x4 __attribute__((ext_vector_type(4)));

__device__ __forceinline__ float fsig(float x)  { return 1.0f / (1.0f + __expf(-x)); }
__device__ __forceinline__ float ftanh(float x) { return 1.0f - 2.0f / (1.0f + __expf(2.0f * x)); }

// Block = 512 threads = 8 waves, owns 16 batch rows for all 30 steps.
// Wave w computes gate slice: for hidden j in [16w,16w+16), all 4 gate types (nt=0..3 == i,f,g,o).
// A (16x160) = [h(128) | x(16) | 0(16)] split hi/lo f16 in LDS; B = W' in per-wave VGPR fragments.
__global__ __launch_bounds__(512, 2)
void lstm30_kernel(const float* __restrict__ last_obs_rel,
                   const float* __restrict__ h0,
                   const float* __restrict__ c0,
                   const float* __restrict__ W_sp,
                   const float* __restrict__ b_sp,
                   const float* __restrict__ W_ih,
                   const float* __restrict__ b_ih,
                   const float* __restrict__ W_hh,
                   const float* __restrict__ b_hh,
                   const float* __restrict__ W_out,
                   const float* __restrict__ b_out,
                   float* __restrict__ out)
{
    __shared__ _Float16 hA[16][KPAD];   // h_hi | x | zeros
    __shared__ _Float16 lA[16][KPAD];   // h_lo | zeros
    __shared__ float    h32[16][128];   // fp32 h for the W_out reduction

    const int tid  = threadIdx.x;
    const int w    = tid >> 6;   // wave 0..7
    const int L    = tid & 63;   // lane
    const int quad = L >> 4;     // 0..3
    const int col  = L & 15;     // 0..15
    const int base = blockIdx.x << 4;

    // zero A buffers (pad/x regions must be 0 before first MFMA)
    for (int idx = tid; idx < 16 * KPAD; idx += 512) {
        (&hA[0][0])[idx] = (_Float16)0.0f;
        (&lA[0][0])[idx] = (_Float16)0.0f;
    }

    // ---- B fragments: W'[k][G], G = nt*128 + 16w + col (gate-type nt, hidden 16w+col) ----
    // lane holds B[k = kc*32 + quad*8 + j][n=col] per (nt,kc)
    half8 Wf[4][5];
    float bias[4];
    #pragma unroll
    for (int nt = 0; nt < 4; ++nt) {
        const int G = nt * 128 + w * 16 + col;
        bias[nt] = b_ih[G] + b_hh[G];
        #pragma unroll
        for (int kc = 0; kc < 5; ++kc) {
            const int k0 = kc * 32 + quad * 8;
            float v[8];
            if (k0 < 128) {
                const float4 a = *(const float4*)&W_hh[G * 128 + k0];
                const float4 b = *(const float4*)&W_hh[G * 128 + k0 + 4];
                v[0]=a.x; v[1]=a.y; v[2]=a.z; v[3]=a.w;
                v[4]=b.x; v[5]=b.y; v[6]=b.z; v[7]=b.w;
            } else if (k0 < 144) {
                const float4 a = *(const float4*)&W_ih[G * 16 + (k0 - 128)];
                const float4 b = *(const float4*)&W_ih[G * 16 + (k0 - 128) + 4];
                v[0]=a.x; v[1]=a.y; v[2]=a.z; v[3]=a.w;
                v[4]=b.x; v[5]=b.y; v[6]=b.z; v[7]=b.w;
            } else {
                #pragma unroll
                for (int jj = 0; jj < 8; ++jj) v[jj] = 0.0f;
            }
            half8 hh;
            #pragma unroll
            for (int jj = 0; jj < 8; ++jj) hh[jj] = (_Float16)v[jj];
            Wf[nt][kc] = hh;
        }
    }

    // epilogue constants
    const float wo00 = W_out[L];         // W_out[0][L]
    const float wo01 = W_out[64 + L];    // W_out[0][64+L]
    const float wo10 = W_out[128 + L];   // W_out[1][L]
    const float wo11 = W_out[192 + L];   // W_out[1][64+L]
    const float bo0 = b_out[0], bo1 = b_out[1];
    const float ws0 = W_sp[col * 2 + 0];
    const float ws1 = W_sp[col * 2 + 1];
    const float bs  = b_sp[col];

    // c state: lane owns c[row = quad*4+r][hidden = 16w+col]
    float c[4];
    #pragma unroll
    for (int r = 0; r < 4; ++r)
        c[r] = c0[(base + quad * 4 + r) * 128 + w * 16 + col];

    __syncthreads();   // zero-fill visible

    // h0 -> split hi/lo into LDS (coalesced: base*128 + idx is contiguous)
    for (int idx = tid; idx < 16 * 128; idx += 512) {
        const int r = idx >> 7, k = idx & 127;
        const float v = h0[base * 128 + idx];
        const _Float16 hi = (_Float16)v;
        hA[r][k] = hi;
        lA[r][k] = (_Float16)(v - (float)hi);
        h32[r][k] = v;
    }

    // x0 = tanh(last_obs_rel @ W_sp^T + b_sp); wave w -> rows 2w, 2w+1
    if (L < 32) {
        const int rowx = 2 * w + quad;   // quad in {0,1} here
        const float p0 = last_obs_rel[(base + rowx) * 2 + 0];
        const float p1 = last_obs_rel[(base + rowx) * 2 + 1];
        const float xv = ftanh(ws0 * p0 + ws1 * p1 + bs);
        hA[rowx][128 + col] = (_Float16)xv;
    }
    __syncthreads();

    const int r0 = 2 * w;
    const int j  = w * 16 + col;

    for (int s = 0; s < TSTEPS; ++s) {
        // A fragments: lane holds A[m=col][k = kc*32 + quad*8 + j]
        half8 aH[5], aL[4];
        #pragma unroll
        for (int kc = 0; kc < 5; ++kc)
            aH[kc] = *(const half8*)&hA[col][kc * 32 + quad * 8];
        #pragma unroll
        for (int kc = 0; kc < 4; ++kc)
            aL[kc] = *(const half8*)&lA[col][kc * 32 + quad * 8];

        f32x4 acc[4];
        #pragma unroll
        for (int nt = 0; nt < 4; ++nt) {
            f32x4 t = {bias[nt], bias[nt], bias[nt], bias[nt]};
            acc[nt] = t;
        }
        #pragma unroll
        for (int kc = 0; kc < 5; ++kc)
            #pragma unroll
            for (int nt = 0; nt < 4; ++nt)
                acc[nt] = __builtin_amdgcn_mfma_f32_16x16x32_f16(aH[kc], Wf[nt][kc], acc[nt], 0, 0, 0);
        #pragma unroll
        for (int kc = 0; kc < 4; ++kc)   // lo pass: x-region of lA is all zero, skip kc=4
            #pragma unroll
            for (int nt = 0; nt < 4; ++nt)
                acc[nt] = __builtin_amdgcn_mfma_f32_16x16x32_f16(aL[kc], Wf[nt][kc], acc[nt], 0, 0, 0);

        __syncthreads();   // (A) everyone done reading hA/lA before rewrite

        // LSTM cell: acc[0..3][r] = i,f,g,o for (row=quad*4+r, hidden=j)
        #pragma unroll
        for (int r = 0; r < 4; ++r) {
            const int row = quad * 4 + r;
            const float gi = fsig(acc[0][r]);
            const float gf = fsig(acc[1][r]);
            const float gg = ftanh(acc[2][r]);
            const float go = fsig(acc[3][r]);
            c[r] = gf * c[r] + gi * gg;
            const float h = go * ftanh(c[r]);
            const _Float16 hi = (_Float16)h;
            hA[row][j] = hi;
            lA[row][j] = (_Float16)(h - (float)hi);
            h32[row][j] = h;
        }

        __syncthreads();   // (B) h visible

        // rel_pos for rows r0, r0+1 (dot-128 over all waves' hidden units)
        const float ha0 = h32[r0][L],     hb0 = h32[r0][64 + L];
        const float ha1 = h32[r0 + 1][L], hb1 = h32[r0 + 1][64 + L];
        float p00 = ha0 * wo00 + hb0 * wo01;
        float p01 = ha0 * wo10 + hb0 * wo11;
        float p10 = ha1 * wo00 + hb1 * wo01;
        float p11 = ha1 * wo10 + hb1 * wo11;
        #pragma unroll
        for (int off = 32; off >= 1; off >>= 1) {
            p00 += __shfl_xor(p00, off, 64);
            p01 += __shfl_xor(p01, off, 64);
            p10 += __shfl_xor(p10, off, 64);
            p11 += __shfl_xor(p11, off, 64);
        }
        p00 += bo0; p01 += bo1; p10 += bo0; p11 += bo1;

        if (L == 0) {
            float2 v = make_float2(p00, p01);
            *(float2*)&out[(base + r0) * (TSTEPS * 2) + s * 2] = v;
        } else if (L == 1) {
            float2 v = make_float2(p10, p11);
            *(float2*)&out[(base + r0 + 1) * (TSTEPS * 2) + s * 2] = v;
        }

        // x_new = tanh(rel_pos @ W_sp^T + b_sp) into A's x region (single f16; lo stays 0)
        if (L < 32) {
            const int rowx = r0 + (L >> 4);
            const float q0 = (L < 16) ? p00 : p10;
            const float q1 = (L < 16) ? p01 : p11;
            const float xv = ftanh(ws0 * q0 + ws1 * q1 + bs);
            hA[rowx][128 + col] = (_Float16)xv;
        }

        __syncthreads();   // (C) x/h ready for next step's A reads
    }
}

extern "C" void kernel_launch(void* const* d_in, const int* in_sizes, int n_in,
                              void* d_out, int out_size, void* d_ws, size_t ws_size,
                              hipStream_t stream) {
    const float* last_obs_rel = (const float*)d_in[1];
    const float* h0    = (const float*)d_in[2];
    const float* c0    = (const float*)d_in[3];
    const float* W_sp  = (const float*)d_in[4];
    const float* b_sp  = (const float*)d_in[5];
    const float* W_ih  = (const float*)d_in[6];
    const float* b_ih  = (const float*)d_in[7];
    const float* W_hh  = (const float*)d_in[8];
    const float* b_hh  = (const float*)d_in[9];
    const float* W_out = (const float*)d_in[10];
    const float* b_out = (const float*)d_in[11];
    float* out = (float*)d_out;

    const int batch = in_sizes[2] / 128;   // 65536
    lstm30_kernel<<<dim3(batch / 16), dim3(512), 0, stream>>>(
        last_obs_rel, h0, c0, W_sp, b_sp, W_ih, b_ih, W_hh, b_hh, W_out, b_out, out);
}

// Round 2
// 1091.508 us; speedup vs baseline: 1.4178x; 1.4178x over previous
//
#include <hip/hip_runtime.h>

#define TSTEPS 30
#define KPAD 168   // 160 K + 8 pad halfs -> 336B row stride; frag reads land 2-way/bank (free, m136)

typedef _Float16 half8 __attribute__((ext_vector_type(8)));
typedef float f32x4 __attribute__((ext_vector_type(4)));

__device__ __forceinline__ float fsig(float x)  { return 1.0f / (1.0f + __expf(-x)); }
__device__ __forceinline__ float ftanh(float x) { return 1.0f - 2.0f / (1.0f + __expf(2.0f * x)); }

// Block = 512 threads = 8 waves, owns 32 batch rows (2 row-tiles of 16) for all 30 steps.
// Wave w: gate slice for hidden j in [16w,16w+16), all 4 gate types, both row-tiles.
// Fold: x_{t} = tanh(M·h_t + m0), rel_{t-1} = W_out·h_t + b_out  (M = W_sp@W_out) —
// both computed as extra MFMA columns in the same pass as the gates' h-part.
// Waves 0/1: xpre for tile 0/1. Waves 2/3: relpre for tile 0/1 (output delayed 1 step).
__global__ __launch_bounds__(512, 2)
void lstm30_kernel(const float* __restrict__ last_obs_rel,
                   const float* __restrict__ h0,
                   const float* __restrict__ c0,
                   const float* __restrict__ W_sp,
                   const float* __restrict__ b_sp,
                   const float* __restrict__ W_ih,
                   const float* __restrict__ b_ih,
                   const float* __restrict__ W_hh,
                   const float* __restrict__ b_hh,
                   const float* __restrict__ W_out,
                   const float* __restrict__ b_out,
                   float* __restrict__ out)
{
    __shared__ _Float16 hA[32][KPAD];   // h_hi(128) | x(16) | 0(24)
    __shared__ _Float16 lA[32][KPAD];   // h_lo(128) | 0

    const int tid  = threadIdx.x;
    const int w    = tid >> 6;
    const int L    = tid & 63;
    const int quad = L >> 4;
    const int col  = L & 15;
    const int base = blockIdx.x << 5;   // 32 rows/block

    // zero A buffers (pad + x regions must be 0 before first MFMA)
    for (int idx = tid; idx < 32 * KPAD; idx += 512) {
        (&hA[0][0])[idx] = (_Float16)0.0f;
        (&lA[0][0])[idx] = (_Float16)0.0f;
    }

    // ---- gate B fragments: W'[k][G], G = nt*128 + 16w + col ----
    half8 Wf[4][5];
    float bias[4];
    #pragma unroll
    for (int nt = 0; nt < 4; ++nt) {
        const int G = nt * 128 + w * 16 + col;
        bias[nt] = b_ih[G] + b_hh[G];
        #pragma unroll
        for (int kc = 0; kc < 5; ++kc) {
            const int k0 = kc * 32 + quad * 8;
            float v[8];
            if (k0 < 128) {
                const float4 a = *(const float4*)&W_hh[G * 128 + k0];
                const float4 b = *(const float4*)&W_hh[G * 128 + k0 + 4];
                v[0]=a.x; v[1]=a.y; v[2]=a.z; v[3]=a.w;
                v[4]=b.x; v[5]=b.y; v[6]=b.z; v[7]=b.w;
            } else if (k0 < 144) {
                const float4 a = *(const float4*)&W_ih[G * 16 + (k0 - 128)];
                const float4 b = *(const float4*)&W_ih[G * 16 + (k0 - 128) + 4];
                v[0]=a.x; v[1]=a.y; v[2]=a.z; v[3]=a.w;
                v[4]=b.x; v[5]=b.y; v[6]=b.z; v[7]=b.w;
            } else {
                #pragma unroll
                for (int jj = 0; jj < 8; ++jj) v[jj] = 0.0f;
            }
            half8 hh;
            #pragma unroll
            for (int jj = 0; jj < 8; ++jj) hh[jj] = (_Float16)v[jj];
            Wf[nt][kc] = hh;
        }
    }

    // per-lane small constants
    const float ws0 = W_sp[col * 2 + 0];
    const float ws1 = W_sp[col * 2 + 1];
    const float bs  = b_sp[col];
    const float bo0 = b_out[0], bo1 = b_out[1];

    // ---- extra B fragments (K=128 only): waves 0/1 -> M^T cols, waves 2/3 -> W_out cols ----
    half8 Ef[4];
    float einit = 0.0f;
    if (w < 4) {
        #pragma unroll
        for (int kc = 0; kc < 4; ++kc) {
            const int k0 = kc * 32 + quad * 8;
            const float4 a0 = *(const float4*)&W_out[k0];
            const float4 a1 = *(const float4*)&W_out[k0 + 4];
            const float4 b0 = *(const float4*)&W_out[128 + k0];
            const float4 b1 = *(const float4*)&W_out[128 + k0 + 4];
            float r0[8] = {a0.x,a0.y,a0.z,a0.w,a1.x,a1.y,a1.z,a1.w};
            float r1[8] = {b0.x,b0.y,b0.z,b0.w,b1.x,b1.y,b1.z,b1.w};
            half8 hh;
            if (w < 2) {
                #pragma unroll
                for (int jj = 0; jj < 8; ++jj)
                    hh[jj] = (_Float16)(ws0 * r0[jj] + ws1 * r1[jj]);   // M[e=col][k]
            } else {
                #pragma unroll
                for (int jj = 0; jj < 8; ++jj)
                    hh[jj] = (_Float16)((col == 0) ? r0[jj] : (col == 1) ? r1[jj] : 0.0f);
            }
            Ef[kc] = hh;
        }
        einit = (w < 2) ? (ws0 * bo0 + ws1 * bo1 + bs)
                        : ((col == 0) ? bo0 : (col == 1) ? bo1 : 0.0f);
    }

    // c state: lane owns c[tile][r] for row = tile*16 + quad*4 + r, hidden = 16w+col
    float c[2][4];
    #pragma unroll
    for (int tt = 0; tt < 2; ++tt)
        #pragma unroll
        for (int r = 0; r < 4; ++r)
            c[tt][r] = c0[(base + tt * 16 + quad * 4 + r) * 128 + w * 16 + col];

    __syncthreads();   // zero-fill visible before h0/x0 writes

    // h0 -> hi/lo split (coalesced)
    for (int idx = tid; idx < 32 * 128; idx += 512) {
        const int r = idx >> 7, k = idx & 127;
        const float v = h0[base * 128 + idx];
        const _Float16 hi = (_Float16)v;
        hA[r][k] = hi;
        lA[r][k] = (_Float16)(v - (float)hi);
    }
    // x0 = tanh(W_sp·last_obs_rel + b_sp): thread t -> row t>>4, e = t&15 (== col)
    {
        const int rowx = tid >> 4;
        const float p0 = last_obs_rel[(base + rowx) * 2 + 0];
        const float p1 = last_obs_rel[(base + rowx) * 2 + 1];
        hA[rowx][128 + col] = (_Float16)ftanh(ws0 * p0 + ws1 * p1 + bs);
    }
    __syncthreads();

    const int j = w * 16 + col;

    for (int t = 0; t < TSTEPS; ++t) {
        f32x4 acc[2][4];
        f32x4 eacc;
        #pragma unroll
        for (int tt = 0; tt < 2; ++tt)
            #pragma unroll
            for (int nt = 0; nt < 4; ++nt) {
                f32x4 tmp = {bias[nt], bias[nt], bias[nt], bias[nt]};
                acc[tt][nt] = tmp;
            }
        {
            f32x4 tmp = {einit, einit, einit, einit};
            eacc = tmp;
        }

        // ---- Phase 1: K=128 (h) MFMAs, hi then lo, per row-tile ----
        #pragma unroll
        for (int tt = 0; tt < 2; ++tt) {
            const int arow = tt * 16 + col;
            half8 aH[4];
            #pragma unroll
            for (int kc = 0; kc < 4; ++kc)
                aH[kc] = *(const half8*)&hA[arow][kc * 32 + quad * 8];
            #pragma unroll
            for (int kc = 0; kc < 4; ++kc)
                #pragma unroll
                for (int nt = 0; nt < 4; ++nt)
                    acc[tt][nt] = __builtin_amdgcn_mfma_f32_16x16x32_f16(aH[kc], Wf[nt][kc], acc[tt][nt], 0, 0, 0);
            if (w < 4 && (w & 1) == tt) {
                #pragma unroll
                for (int kc = 0; kc < 4; ++kc)
                    eacc = __builtin_amdgcn_mfma_f32_16x16x32_f16(aH[kc], Ef[kc], eacc, 0, 0, 0);
            }
            half8 aL[4];
            #pragma unroll
            for (int kc = 0; kc < 4; ++kc)
                aL[kc] = *(const half8*)&lA[arow][kc * 32 + quad * 8];
            #pragma unroll
            for (int kc = 0; kc < 4; ++kc)
                #pragma unroll
                for (int nt = 0; nt < 4; ++nt)
                    acc[tt][nt] = __builtin_amdgcn_mfma_f32_16x16x32_f16(aL[kc], Wf[nt][kc], acc[tt][nt], 0, 0, 0);
            if (w < 4 && (w & 1) == tt) {
                #pragma unroll
                for (int kc = 0; kc < 4; ++kc)
                    eacc = __builtin_amdgcn_mfma_f32_16x16x32_f16(aL[kc], Ef[kc], eacc, 0, 0, 0);
            }
        }

        // ---- Phase 1.5: x_t write (waves 0/1), rel_{t-1} store (waves 2/3) ----
        if (w < 2 && t > 0) {
            #pragma unroll
            for (int r = 0; r < 4; ++r)
                hA[w * 16 + quad * 4 + r][128 + col] = (_Float16)ftanh(eacc[r]);
        }
        if ((w == 2 || w == 3) && t > 0 && col < 2) {
            #pragma unroll
            for (int r = 0; r < 4; ++r) {
                const int row = base + (w - 2) * 16 + quad * 4 + r;
                out[row * (TSTEPS * 2) + (t - 1) * 2 + col] = eacc[r];
            }
        }
        __syncthreads();   // x_t visible; all h_t frag reads done

        // ---- Phase 2: K=32 (x) MFMA + cell ----
        #pragma unroll
        for (int tt = 0; tt < 2; ++tt) {
            const half8 xa = *(const half8*)&hA[tt * 16 + col][128 + quad * 8];
            #pragma unroll
            for (int nt = 0; nt < 4; ++nt)
                acc[tt][nt] = __builtin_amdgcn_mfma_f32_16x16x32_f16(xa, Wf[nt][4], acc[tt][nt], 0, 0, 0);
        }
        #pragma unroll
        for (int tt = 0; tt < 2; ++tt)
            #pragma unroll
            for (int r = 0; r < 4; ++r) {
                const int row = tt * 16 + quad * 4 + r;
                const float gi = fsig(acc[tt][0][r]);
                const float gf = fsig(acc[tt][1][r]);
                const float gg = ftanh(acc[tt][2][r]);
                const float go = fsig(acc[tt][3][r]);
                c[tt][r] = gf * c[tt][r] + gi * gg;
                const float h = go * ftanh(c[tt][r]);
                const _Float16 hi = (_Float16)h;
                hA[row][j] = hi;
                lA[row][j] = (_Float16)(h - (float)hi);
            }
        __syncthreads();   // h_{t+1} visible for next phase 1
    }

    // ---- tail: rel_{29} from h_30 (waves 2/3) ----
    if (w == 2 || w == 3) {
        const int tt = w - 2;
        f32x4 eacc;
        { f32x4 tmp = {einit, einit, einit, einit}; eacc = tmp; }
        const int arow = tt * 16 + col;
        half8 aH[4], aL[4];
        #pragma unroll
        for (int kc = 0; kc < 4; ++kc)
            aH[kc] = *(const half8*)&hA[arow][kc * 32 + quad * 8];
        #pragma unroll
        for (int kc = 0; kc < 4; ++kc)
            eacc = __builtin_amdgcn_mfma_f32_16x16x32_f16(aH[kc], Ef[kc], eacc, 0, 0, 0);
        #pragma unroll
        for (int kc = 0; kc < 4; ++kc)
            aL[kc] = *(const half8*)&lA[arow][kc * 32 + quad * 8];
        #pragma unroll
        for (int kc = 0; kc < 4; ++kc)
            eacc = __builtin_amdgcn_mfma_f32_16x16x32_f16(aL[kc], Ef[kc], eacc, 0, 0, 0);
        if (col < 2) {
            #pragma unroll
            for (int r = 0; r < 4; ++r) {
                const int row = base + tt * 16 + quad * 4 + r;
                out[row * (TSTEPS * 2) + (TSTEPS - 1) * 2 + col] = eacc[r];
            }
        }
    }
}

extern "C" void kernel_launch(void* const* d_in, const int* in_sizes, int n_in,
                              void* d_out, int out_size, void* d_ws, size_t ws_size,
                              hipStream_t stream) {
    const float* last_obs_rel = (const float*)d_in[1];
    const float* h0    = (const float*)d_in[2];
    const float* c0    = (const float*)d_in[3];
    const float* W_sp  = (const float*)d_in[4];
    const float* b_sp  = (const float*)d_in[5];
    const float* W_ih  = (const float*)d_in[6];
    const float* b_ih  = (const float*)d_in[7];
    const float* W_hh  = (const float*)d_in[8];
    const float* b_hh  = (const float*)d_in[9];
    const float* W_out = (const float*)d_in[10];
    const float* b_out = (const float*)d_in[11];
    float* out = (float*)d_out;

    const int batch = in_sizes[2] / 128;   // 65536
    lstm30_kernel<<<dim3(batch / 32), dim3(512), 0, stream>>>(
        last_obs_rel, h0, c0, W_sp, b_sp, W_ih, b_ih, W_hh, b_hh, W_out, b_out, out);
}

// Round 3
// 752.376 us; speedup vs baseline: 2.0569x; 1.4507x over previous
//
#include <hip/hip_runtime.h>

#define TSTEPS 30
#define KPAD 168   // 160 K + 8 pad halfs -> 336B row stride; frag reads land 2-way/bank (free, m136)

#define LOG2E     1.44269504f
#define TWO_LOG2E 2.88539008f

typedef _Float16 half8 __attribute__((ext_vector_type(8)));
typedef float f32x4 __attribute__((ext_vector_type(4)));

__device__ __forceinline__ float fexp2(float x) { return __builtin_amdgcn_exp2f(x); }
__device__ __forceinline__ float frcp(float x)  { return __builtin_amdgcn_rcpf(x); }
// pre-scaled forms: sigmoid arg pre-multiplied by log2e, tanh arg by 2*log2e
__device__ __forceinline__ float fsig_pre(float x)  { return frcp(1.0f + fexp2(-x)); }
__device__ __forceinline__ float ftanh_pre(float x) { return 1.0f - 2.0f * frcp(1.0f + fexp2(x)); }

// Block = 512 threads = 8 waves, owns 32 batch rows (2 row-tiles of 16) for all 30 steps.
// Wave w: gate slice for hidden j in [16w,16w+16), all 4 gate types, both row-tiles.
// Fold: x_{t} = tanh(M·h_t + m0), rel_{t-1} = W_out·h_t + b_out  (M = W_sp@W_out) —
// both computed as extra MFMA columns in the same pass as the gates' h-part.
// Gate weights pre-scaled by log2e (i,f,o) / 2log2e (g) so the epilogue uses raw
// v_exp_f32/v_rcp_f32 with no argument scaling.
__global__ __launch_bounds__(512, 2)
void lstm30_kernel(const float* __restrict__ last_obs_rel,
                   const float* __restrict__ h0,
                   const float* __restrict__ c0,
                   const float* __restrict__ W_sp,
                   const float* __restrict__ b_sp,
                   const float* __restrict__ W_ih,
                   const float* __restrict__ b_ih,
                   const float* __restrict__ W_hh,
                   const float* __restrict__ b_hh,
                   const float* __restrict__ W_out,
                   const float* __restrict__ b_out,
                   float* __restrict__ out)
{
    __shared__ _Float16 hA[32][KPAD];   // h_hi(128) | x(16) | 0(24)
    __shared__ _Float16 lA[32][KPAD];   // h_lo(128) | 0

    const int tid  = threadIdx.x;
    const int w    = tid >> 6;
    const int L    = tid & 63;
    const int quad = L >> 4;
    const int col  = L & 15;
    const int base = blockIdx.x << 5;   // 32 rows/block

    // zero A buffers (pad + x regions must be 0 before first MFMA)
    for (int idx = tid; idx < 32 * KPAD; idx += 512) {
        (&hA[0][0])[idx] = (_Float16)0.0f;
        (&lA[0][0])[idx] = (_Float16)0.0f;
    }

    // ---- gate B fragments: W'[k][G], G = nt*128 + 16w + col, pre-scaled ----
    half8 Wf[4][5];
    float bias[4];
    #pragma unroll
    for (int nt = 0; nt < 4; ++nt) {
        const int G = nt * 128 + w * 16 + col;
        const float gsc = (nt == 2) ? TWO_LOG2E : LOG2E;
        bias[nt] = (b_ih[G] + b_hh[G]) * gsc;
        #pragma unroll
        for (int kc = 0; kc < 5; ++kc) {
            const int k0 = kc * 32 + quad * 8;
            float v[8];
            if (k0 < 128) {
                const float4 a = *(const float4*)&W_hh[G * 128 + k0];
                const float4 b = *(const float4*)&W_hh[G * 128 + k0 + 4];
                v[0]=a.x; v[1]=a.y; v[2]=a.z; v[3]=a.w;
                v[4]=b.x; v[5]=b.y; v[6]=b.z; v[7]=b.w;
            } else if (k0 < 144) {
                const float4 a = *(const float4*)&W_ih[G * 16 + (k0 - 128)];
                const float4 b = *(const float4*)&W_ih[G * 16 + (k0 - 128) + 4];
                v[0]=a.x; v[1]=a.y; v[2]=a.z; v[3]=a.w;
                v[4]=b.x; v[5]=b.y; v[6]=b.z; v[7]=b.w;
            } else {
                #pragma unroll
                for (int jj = 0; jj < 8; ++jj) v[jj] = 0.0f;
            }
            half8 hh;
            #pragma unroll
            for (int jj = 0; jj < 8; ++jj) hh[jj] = (_Float16)(v[jj] * gsc);
            Wf[nt][kc] = hh;
        }
    }

    // per-lane small constants
    const float ws0 = W_sp[col * 2 + 0];
    const float ws1 = W_sp[col * 2 + 1];
    const float bs  = b_sp[col];
    const float bo0 = b_out[0], bo1 = b_out[1];

    // ---- extra B fragments (K=128 only): waves 0/1 -> M^T cols (pre-scaled 2log2e for tanh),
    //      waves 2/3 -> W_out cols (raw, output path) ----
    half8 Ef[4];
    float einit = 0.0f;
    if (w < 4) {
        #pragma unroll
        for (int kc = 0; kc < 4; ++kc) {
            const int k0 = kc * 32 + quad * 8;
            const float4 a0 = *(const float4*)&W_out[k0];
            const float4 a1 = *(const float4*)&W_out[k0 + 4];
            const float4 b0 = *(const float4*)&W_out[128 + k0];
            const float4 b1 = *(const float4*)&W_out[128 + k0 + 4];
            float r0[8] = {a0.x,a0.y,a0.z,a0.w,a1.x,a1.y,a1.z,a1.w};
            float r1[8] = {b0.x,b0.y,b0.z,b0.w,b1.x,b1.y,b1.z,b1.w};
            half8 hh;
            if (w < 2) {
                #pragma unroll
                for (int jj = 0; jj < 8; ++jj)
                    hh[jj] = (_Float16)((ws0 * r0[jj] + ws1 * r1[jj]) * TWO_LOG2E);   // M[e=col][k]
            } else {
                #pragma unroll
                for (int jj = 0; jj < 8; ++jj)
                    hh[jj] = (_Float16)((col == 0) ? r0[jj] : (col == 1) ? r1[jj] : 0.0f);
            }
            Ef[kc] = hh;
        }
        einit = (w < 2) ? (ws0 * bo0 + ws1 * bo1 + bs) * TWO_LOG2E
                        : ((col == 0) ? bo0 : (col == 1) ? bo1 : 0.0f);
    }

    // c state: lane owns c[tile][r] for row = tile*16 + quad*4 + r, hidden = 16w+col
    float c[2][4];
    #pragma unroll
    for (int tt = 0; tt < 2; ++tt)
        #pragma unroll
        for (int r = 0; r < 4; ++r)
            c[tt][r] = c0[(base + tt * 16 + quad * 4 + r) * 128 + w * 16 + col];

    __syncthreads();   // zero-fill visible before h0/x0 writes

    // h0 -> hi/lo split (coalesced)
    for (int idx = tid; idx < 32 * 128; idx += 512) {
        const int r = idx >> 7, k = idx & 127;
        const float v = h0[base * 128 + idx];
        const _Float16 hi = (_Float16)v;
        hA[r][k] = hi;
        lA[r][k] = (_Float16)(v - (float)hi);
    }
    // x0 = tanh(W_sp·last_obs_rel + b_sp): thread t -> row t>>4, e = t&15 (== col)
    {
        const int rowx = tid >> 4;
        const float p0 = last_obs_rel[(base + rowx) * 2 + 0];
        const float p1 = last_obs_rel[(base + rowx) * 2 + 1];
        hA[rowx][128 + col] = (_Float16)ftanh_pre(TWO_LOG2E * (ws0 * p0 + ws1 * p1 + bs));
    }
    __syncthreads();

    const int j = w * 16 + col;

    for (int t = 0; t < TSTEPS; ++t) {
        f32x4 acc[2][4];
        f32x4 eacc;
        #pragma unroll
        for (int tt = 0; tt < 2; ++tt)
            #pragma unroll
            for (int nt = 0; nt < 4; ++nt) {
                f32x4 tmp = {bias[nt], bias[nt], bias[nt], bias[nt]};
                acc[tt][nt] = tmp;
            }
        {
            f32x4 tmp = {einit, einit, einit, einit};
            eacc = tmp;
        }

        // ---- Phase 1: K=128 (h) MFMAs, hi then lo, per row-tile ----
        #pragma unroll
        for (int tt = 0; tt < 2; ++tt) {
            const int arow = tt * 16 + col;
            half8 aH[4];
            #pragma unroll
            for (int kc = 0; kc < 4; ++kc)
                aH[kc] = *(const half8*)&hA[arow][kc * 32 + quad * 8];
            #pragma unroll
            for (int kc = 0; kc < 4; ++kc)
                #pragma unroll
                for (int nt = 0; nt < 4; ++nt)
                    acc[tt][nt] = __builtin_amdgcn_mfma_f32_16x16x32_f16(aH[kc], Wf[nt][kc], acc[tt][nt], 0, 0, 0);
            if (w < 4 && (w & 1) == tt) {
                #pragma unroll
                for (int kc = 0; kc < 4; ++kc)
                    eacc = __builtin_amdgcn_mfma_f32_16x16x32_f16(aH[kc], Ef[kc], eacc, 0, 0, 0);
            }
            half8 aL[4];
            #pragma unroll
            for (int kc = 0; kc < 4; ++kc)
                aL[kc] = *(const half8*)&lA[arow][kc * 32 + quad * 8];
            #pragma unroll
            for (int kc = 0; kc < 4; ++kc)
                #pragma unroll
                for (int nt = 0; nt < 4; ++nt)
                    acc[tt][nt] = __builtin_amdgcn_mfma_f32_16x16x32_f16(aL[kc], Wf[nt][kc], acc[tt][nt], 0, 0, 0);
            if (w < 4 && (w & 1) == tt) {
                #pragma unroll
                for (int kc = 0; kc < 4; ++kc)
                    eacc = __builtin_amdgcn_mfma_f32_16x16x32_f16(aL[kc], Ef[kc], eacc, 0, 0, 0);
            }
        }

        // ---- Phase 1.5: x_t write (waves 0/1), rel_{t-1} store (waves 2/3) ----
        if (w < 2 && t > 0) {
            #pragma unroll
            for (int r = 0; r < 4; ++r)
                hA[w * 16 + quad * 4 + r][128 + col] = (_Float16)ftanh_pre(eacc[r]);
        }
        if ((w == 2 || w == 3) && t > 0 && col < 2) {
            #pragma unroll
            for (int r = 0; r < 4; ++r) {
                const int row = base + (w - 2) * 16 + quad * 4 + r;
                out[row * (TSTEPS * 2) + (t - 1) * 2 + col] = eacc[r];
            }
        }
        __syncthreads();   // x_t visible; all h_t frag reads done

        // ---- Phase 2: K=32 (x) MFMA + cell ----
        #pragma unroll
        for (int tt = 0; tt < 2; ++tt) {
            const half8 xa = *(const half8*)&hA[tt * 16 + col][128 + quad * 8];
            #pragma unroll
            for (int nt = 0; nt < 4; ++nt)
                acc[tt][nt] = __builtin_amdgcn_mfma_f32_16x16x32_f16(xa, Wf[nt][4], acc[tt][nt], 0, 0, 0);
        }
        #pragma unroll
        for (int tt = 0; tt < 2; ++tt)
            #pragma unroll
            for (int r = 0; r < 4; ++r) {
                const int row = tt * 16 + quad * 4 + r;
                const float gi = fsig_pre(acc[tt][0][r]);
                const float gf = fsig_pre(acc[tt][1][r]);
                const float gg = ftanh_pre(acc[tt][2][r]);
                const float go = fsig_pre(acc[tt][3][r]);
                c[tt][r] = gf * c[tt][r] + gi * gg;
                const float h = go * ftanh_pre(TWO_LOG2E * c[tt][r]);
                const _Float16 hi = (_Float16)h;
                hA[row][j] = hi;
                lA[row][j] = (_Float16)(h - (float)hi);
            }
        __syncthreads();   // h_{t+1} visible for next phase 1
    }

    // ---- tail: rel_{29} from h_30 (waves 2/3) ----
    if (w == 2 || w == 3) {
        const int tt = w - 2;
        f32x4 eacc;
        { f32x4 tmp = {einit, einit, einit, einit}; eacc = tmp; }
        const int arow = tt * 16 + col;
        half8 aH[4], aL[4];
        #pragma unroll
        for (int kc = 0; kc < 4; ++kc)
            aH[kc] = *(const half8*)&hA[arow][kc * 32 + quad * 8];
        #pragma unroll
        for (int kc = 0; kc < 4; ++kc)
            eacc = __builtin_amdgcn_mfma_f32_16x16x32_f16(aH[kc], Ef[kc], eacc, 0, 0, 0);
        #pragma unroll
        for (int kc = 0; kc < 4; ++kc)
            aL[kc] = *(const half8*)&lA[arow][kc * 32 + quad * 8];
        #pragma unroll
        for (int kc = 0; kc < 4; ++kc)
            eacc = __builtin_amdgcn_mfma_f32_16x16x32_f16(aL[kc], Ef[kc], eacc, 0, 0, 0);
        if (col < 2) {
            #pragma unroll
            for (int r = 0; r < 4; ++r) {
                const int row = base + tt * 16 + quad * 4 + r;
                out[row * (TSTEPS * 2) + (TSTEPS - 1) * 2 + col] = eacc[r];
            }
        }
    }
}

extern "C" void kernel_launch(void* const* d_in, const int* in_sizes, int n_in,
                              void* d_out, int out_size, void* d_ws, size_t ws_size,
                              hipStream_t stream) {
    const float* last_obs_rel = (const float*)d_in[1];
    const float* h0    = (const float*)d_in[2];
    const float* c0    = (const float*)d_in[3];
    const float* W_sp  = (const float*)d_in[4];
    const float* b_sp  = (const float*)d_in[5];
    const float* W_ih  = (const float*)d_in[6];
    const float* b_ih  = (const float*)d_in[7];
    const float* W_hh  = (const float*)d_in[8];
    const float* b_hh  = (const float*)d_in[9];
    const float* W_out = (const float*)d_in[10];
    const float* b_out = (const float*)d_in[11];
    float* out = (float*)d_out;

    const int batch = in_sizes[2] / 128;   // 65536
    lstm30_kernel<<<dim3(batch / 32), dim3(512), 0, stream>>>(
        last_obs_rel, h0, c0, W_sp, b_sp, W_ih, b_ih, W_hh, b_hh, W_out, b_out, out);
}